// Round 16
// baseline (267.408 us; speedup 1.0000x reference)
//
#include <hip/hip_runtime.h>
#include <stdint.h>

#define B_ 512
#define L_ 48
#define D_ 256

typedef __attribute__((ext_vector_type(8))) short bf16x8;
typedef __attribute__((ext_vector_type(4))) short bf16x4;
typedef __attribute__((ext_vector_type(4))) float f32x4;
typedef __attribute__((ext_vector_type(4))) int i32x4;

__device__ __forceinline__ short f2bf(float f) {
    union { float f; unsigned u; } v; v.f = f;
    unsigned u = v.u;
    unsigned r = (u + 0x7FFFu + ((u >> 16) & 1u)) >> 16;
    return (short)r;
}
__device__ __forceinline__ float bf2f(short s) {
    union { unsigned u; float f; } v; v.u = ((unsigned)(unsigned short)s) << 16;
    return v.f;
}

// -------- weight prep: per-row symmetric i8 quant of [w_hh;w_h] and w_ih -------
__global__ __launch_bounds__(256) void k_prep(const float* __restrict__ w_hh,
                                              const float* __restrict__ w_h,
                                              const float* __restrict__ w_ih,
                                              signed char* __restrict__ W1q,
                                              signed char* __restrict__ W2q,
                                              float* __restrict__ qA,
                                              float* __restrict__ qC) {
    int w = threadIdx.x >> 6, lane = threadIdx.x & 63;
    int R = blockIdx.x * 4 + w;
    if (R >= 1584) return;
    const float* src;
    signed char* dst;
    bool isA = (R < 816);
    if (R < 768)      { src = w_hh + (size_t)R * 256;         dst = W1q + (size_t)R * 256; }
    else if (R < 816) { src = w_h + (size_t)(R - 768) * 256;  dst = W1q + (size_t)R * 256; }
    else              { src = w_ih + (size_t)(R - 816) * 256; dst = W2q + (size_t)(R - 816) * 256; }
    float4 v = *(const float4*)(src + lane * 4);
    float m = fmaxf(fmaxf(fabsf(v.x), fabsf(v.y)), fmaxf(fabsf(v.z), fabsf(v.w)));
    #pragma unroll
    for (int o = 32; o; o >>= 1) m = fmaxf(m, __shfl_xor(m, o));
    float sc = (m > 0.f) ? 127.f / m : 0.f;
    int b0 = __float2int_rn(v.x * sc), b1 = __float2int_rn(v.y * sc);
    int b2 = __float2int_rn(v.z * sc), b3 = __float2int_rn(v.w * sc);
    unsigned word = (unsigned)(b0 & 255) | ((unsigned)(b1 & 255) << 8) |
                    ((unsigned)(b2 & 255) << 16) | ((unsigned)(b3 & 255) << 24);
    ((unsigned*)dst)[lane] = word;
    if (lane == 0) {
        if (isA) qA[R] = m / (127.f * 127.f);
        else     qC[R - 816] = m * 8.f / (127.f * 127.f);
    }
}

// ---------------- embedding GEMM: x = relu(x1@we1^T+b1) + relu(x2@we2^T+b2) ----
__device__ __forceinline__ void gemm_pass(const float* __restrict__ X,
                                          const float* __restrict__ W,
                                          short (*sA)[40], short (*sB)[40],
                                          int m0, int n0, int srow, int sseg,
                                          int mf, int nf, int row16, int kg,
                                          f32x4 (&acc)[2][4]) {
    for (int k0 = 0; k0 < 512; k0 += 32) {
        __syncthreads();
        {
            const float* src = X + (size_t)(m0 + srow) * 512 + k0 + sseg * 8;
            float4 p0 = *(const float4*)(src);
            float4 p1 = *(const float4*)(src + 4);
            bf16x8 v;
            v[0] = f2bf(p0.x); v[1] = f2bf(p0.y); v[2] = f2bf(p0.z); v[3] = f2bf(p0.w);
            v[4] = f2bf(p1.x); v[5] = f2bf(p1.y); v[6] = f2bf(p1.z); v[7] = f2bf(p1.w);
            *(bf16x8*)&sA[srow][sseg * 8] = v;
        }
        {
            const float* src = W + (size_t)(n0 + srow) * 512 + k0 + sseg * 8;
            float4 p0 = *(const float4*)(src);
            float4 p1 = *(const float4*)(src + 4);
            bf16x8 v;
            v[0] = f2bf(p0.x); v[1] = f2bf(p0.y); v[2] = f2bf(p0.z); v[3] = f2bf(p0.w);
            v[4] = f2bf(p1.x); v[5] = f2bf(p1.y); v[6] = f2bf(p1.z); v[7] = f2bf(p1.w);
            *(bf16x8*)&sB[srow][sseg * 8] = v;
        }
        __syncthreads();
        bf16x8 a0 = *(bf16x8*)&sA[(mf + 0) * 16 + row16][kg * 8];
        bf16x8 a1 = *(bf16x8*)&sA[(mf + 1) * 16 + row16][kg * 8];
        #pragma unroll
        for (int j = 0; j < 4; ++j) {
            bf16x8 bv = *(bf16x8*)&sB[(nf + j) * 16 + row16][kg * 8];
            acc[0][j] = __builtin_amdgcn_mfma_f32_16x16x32_bf16(a0, bv, acc[0][j], 0, 0, 0);
            acc[1][j] = __builtin_amdgcn_mfma_f32_16x16x32_bf16(a1, bv, acc[1][j], 0, 0, 0);
        }
    }
}

// pass 2 variant: also accumulates exact-fp32 channel-0 dot of x2 rows vs w_e2[0]
__device__ __forceinline__ void gemm_pass_c0(const float* __restrict__ X,
                                             const float* __restrict__ W,
                                             const float* __restrict__ we2r0,
                                             bool doC0, float& c0acc,
                                             short (*sA)[40], short (*sB)[40],
                                             int m0, int n0, int srow, int sseg,
                                             int mf, int nf, int row16, int kg,
                                             f32x4 (&acc)[2][4]) {
    for (int k0 = 0; k0 < 512; k0 += 32) {
        __syncthreads();
        {
            const float* src = X + (size_t)(m0 + srow) * 512 + k0 + sseg * 8;
            float4 p0 = *(const float4*)(src);
            float4 p1 = *(const float4*)(src + 4);
            if (doC0) {
                const float* wr = we2r0 + k0 + sseg * 8;
                c0acc += p0.x * wr[0] + p0.y * wr[1] + p0.z * wr[2] + p0.w * wr[3]
                       + p1.x * wr[4] + p1.y * wr[5] + p1.z * wr[6] + p1.w * wr[7];
            }
            bf16x8 v;
            v[0] = f2bf(p0.x); v[1] = f2bf(p0.y); v[2] = f2bf(p0.z); v[3] = f2bf(p0.w);
            v[4] = f2bf(p1.x); v[5] = f2bf(p1.y); v[6] = f2bf(p1.z); v[7] = f2bf(p1.w);
            *(bf16x8*)&sA[srow][sseg * 8] = v;
        }
        {
            const float* src = W + (size_t)(n0 + srow) * 512 + k0 + sseg * 8;
            float4 p0 = *(const float4*)(src);
            float4 p1 = *(const float4*)(src + 4);
            bf16x8 v;
            v[0] = f2bf(p0.x); v[1] = f2bf(p0.y); v[2] = f2bf(p0.z); v[3] = f2bf(p0.w);
            v[4] = f2bf(p1.x); v[5] = f2bf(p1.y); v[6] = f2bf(p1.z); v[7] = f2bf(p1.w);
            *(bf16x8*)&sB[srow][sseg * 8] = v;
        }
        __syncthreads();
        bf16x8 a0 = *(bf16x8*)&sA[(mf + 0) * 16 + row16][kg * 8];
        bf16x8 a1 = *(bf16x8*)&sA[(mf + 1) * 16 + row16][kg * 8];
        #pragma unroll
        for (int j = 0; j < 4; ++j) {
            bf16x8 bv = *(bf16x8*)&sB[(nf + j) * 16 + row16][kg * 8];
            acc[0][j] = __builtin_amdgcn_mfma_f32_16x16x32_bf16(a0, bv, acc[0][j], 0, 0, 0);
            acc[1][j] = __builtin_amdgcn_mfma_f32_16x16x32_bf16(a1, bv, acc[1][j], 0, 0, 0);
        }
    }
}

__global__ __launch_bounds__(512) void k_embed(const float* __restrict__ x1,
                                               const float* __restrict__ x2,
                                               const float* __restrict__ w_e1,
                                               const float* __restrict__ b_e1,
                                               const float* __restrict__ w_e2,
                                               const float* __restrict__ b_e2,
                                               short* __restrict__ xb,
                                               float* __restrict__ c0) {
    __shared__ short sA[128][40];
    __shared__ short sB[128][40];
    int bid = blockIdx.x;
    int mt = bid >> 1, nt = bid & 1;
    int m0 = mt * 128, n0 = nt * 128;
    int tid = threadIdx.x;
    int lane = tid & 63, w = tid >> 6;
    int mf = (w & 3) * 2;
    int nf = (w >> 2) * 4;
    int row16 = lane & 15, kg = lane >> 4;
    int srow = tid >> 2, sseg = tid & 3;

    f32x4 acc[2][4], keep[2][4];
    #pragma unroll
    for (int a = 0; a < 2; ++a)
        #pragma unroll
        for (int j = 0; j < 4; ++j) { acc[a][j] = {0.f, 0.f, 0.f, 0.f}; }

    gemm_pass(x1, w_e1, sA, sB, m0, n0, srow, sseg, mf, nf, row16, kg, acc);
    #pragma unroll
    for (int a = 0; a < 2; ++a)
        #pragma unroll
        for (int j = 0; j < 4; ++j) { keep[a][j] = acc[a][j]; acc[a][j] = {0.f, 0.f, 0.f, 0.f}; }

    float c0acc = 0.f;
    const bool doC0 = (nt == 0);
    gemm_pass_c0(x2, w_e2, w_e2, doC0, c0acc, sA, sB, m0, n0, srow, sseg, mf, nf, row16, kg, acc);

    if (doC0) {
        float t = c0acc;
        t += __shfl_xor(t, 1);
        t += __shfl_xor(t, 2);
        if (sseg == 0) c0[m0 + srow] = fmaxf(t + b_e2[0], 0.f);
    }

    #pragma unroll
    for (int a = 0; a < 2; ++a) {
        int mbase = m0 + (mf + a) * 16 + kg * 4;
        #pragma unroll
        for (int j = 0; j < 4; ++j) {
            int n = n0 + (nf + j) * 16 + row16;
            float be1 = b_e1[n], be2 = b_e2[n];
            #pragma unroll
            for (int e = 0; e < 4; ++e) {
                float v1 = fmaxf(keep[a][j][e] + be1, 0.f);
                float v2 = fmaxf(acc[a][j][e] + be2, 0.f);
                xb[(size_t)(mbase + e) * 256 + n] = f2bf(v1 + v2);
            }
        }
    }
}

// --------- quantize x rows to i8 (per-row scale) + fused xw = x . w_x ----------
__global__ __launch_bounds__(256) void k_quant(const short* __restrict__ xb,
                                               const float* __restrict__ w_x,
                                               signed char* __restrict__ xq,
                                               float* __restrict__ xs,
                                               float* __restrict__ xw) {
    int w = threadIdx.x >> 6, lane = threadIdx.x & 63;
    int row = blockIdx.x * 4 + w;
    const short* src = xb + (size_t)row * 256 + lane * 4;
    bf16x4 v = *(const bf16x4*)src;
    float f0 = bf2f(v.x), f1 = bf2f(v.y), f2 = bf2f(v.z), f3 = bf2f(v.w);
    float m = fmaxf(fmaxf(f0, f1), fmaxf(f2, f3));   // x >= 0
    float t = f0 * w_x[lane * 4] + f1 * w_x[lane * 4 + 1] +
              f2 * w_x[lane * 4 + 2] + f3 * w_x[lane * 4 + 3];
    #pragma unroll
    for (int o = 32; o; o >>= 1) {
        m = fmaxf(m, __shfl_xor(m, o));
        t += __shfl_xor(t, o);
    }
    float sc = (m > 0.f) ? 127.f / m : 0.f;
    int b0 = __float2int_rn(f0 * sc), b1 = __float2int_rn(f1 * sc);
    int b2 = __float2int_rn(f2 * sc), b3 = __float2int_rn(f3 * sc);
    unsigned word = (unsigned)(b0 & 255) | ((unsigned)(b1 & 255) << 8) |
                    ((unsigned)(b2 & 255) << 16) | ((unsigned)(b3 & 255) << 24);
    ((unsigned*)xq)[(size_t)row * 64 + lane] = word;
    if (lane == 0) { xs[row] = m / 127.f; xw[row] = t; }
}

// ------------- aux2: cond bitmasks per batch + se = s@w_s^T + b_s --------------
__global__ __launch_bounds__(256) void k_aux2(const float* __restrict__ c0,
                                              const float* __restrict__ s_in,
                                              const float* __restrict__ w_s,
                                              const float* __restrict__ b_s,
                                              unsigned long long* __restrict__ condbits,
                                              float* __restrict__ se) {
    __shared__ float sS[64];
    int b = blockIdx.x;
    int t = threadIdx.x;
    if (t < 64) sS[t] = s_in[b * 64 + t];
    __syncthreads();
    float acc = b_s[t];
    const float* wr = w_s + t * 64;
    #pragma unroll 8
    for (int kk = 0; kk < 64; ++kk) acc += sS[kk] * wr[kk];
    se[(size_t)b * 256 + t] = acc;
    if (t == 0) {
        unsigned long long bits = 0;
        bool run = true;
        const float* cr = c0 + (size_t)b * 48;
        for (int i = 0; i < 48; ++i) {
            if (run) bits |= (1ull << i);
            run = run && (cr[i] == 0.0f);
        }
        condbits[b] = bits;
    }
}

__device__ __forceinline__ void mfma4r(const i32x4 (&a)[4], const i32x4 (&b)[4], i32x4& acc) {
    #pragma unroll
    for (int s = 0; s < 4; ++s)
        acc = __builtin_amdgcn_mfma_i32_16x16x64_i8(a[s], b[s], acc, 0, 0, 0);
}

// ---- persistent scan v9: B2 via i8 MFMA (a' quantized per-step); 2 barriers ----
// 256 blocks x 2 batches, 8 waves. Per wave: redundant score MFMAs -> both
// batches' softmax in-register -> a' i8 to wave-private LDS -> ctx = xT(A) x
// a'(B) in 4 K=64 MFMAs -> barrier -> Phase C + GRU (dequant consts in regs).
__global__ __launch_bounds__(512, 1) void k_scan(const signed char* __restrict__ W1q,
                                                 const signed char* __restrict__ W2q,
                                                 const float* __restrict__ qAg,
                                                 const float* __restrict__ qCg,
                                                 const float* __restrict__ b_hh,
                                                 const float* __restrict__ b_h,
                                                 const float* __restrict__ b_ih,
                                                 const signed char* __restrict__ xq,
                                                 const float* __restrict__ xs,
                                                 const float* __restrict__ xw,
                                                 const unsigned long long* __restrict__ condbits,
                                                 const float* __restrict__ se,
                                                 const float* __restrict__ w_out,
                                                 const float* __restrict__ b_out,
                                                 float* __restrict__ out) {
    __shared__ signed char lWc[8][3][4096];    // slab 8+w: W2 r/z/hn tiles, swizzled
    __shared__ signed char lWs[3][4096];       // score tiles (w_h), swizzled
    __shared__ signed char lXqT[2][256][64];   // x i8 transposed, pitch 64, j>=48 zero
    __shared__ signed char lH8[16][272];       // h as i8 (rows 2-15 stay zero)
    __shared__ signed char lX8[16][272];       // ctx as i8 (rows 2-15 stay zero)
    __shared__ signed char lAq[8][2][64];      // wave-private a' i8 (j>=48 zero)
    __shared__ float lRed[8][2];

    const int tid = threadIdx.x;
    const int w = tid >> 6, lane = tid & 63;
    const int row16 = lane & 15, kg = lane >> 4;
    const int b0 = blockIdx.x * 2;
    const int g1 = 8 + w;
    const int c0 = w * 16 + row16, c1 = g1 * 16 + row16;
    const int swz = (row16 & 7) << 4;
    const float CS = 127.f / 8.f;

    for (int t = tid; t < 1088; t += 512) {   // zero full lH8 and lX8
        ((int*)lH8)[t] = 0;
        ((int*)lX8)[t] = 0;
    }
    if (tid < 256) ((int*)lAq)[tid] = 0;
    {   // stage x TRANSPOSED: thread -> (batch tid>>8, dim tid&255); j>=48 zeroed
        int bq = tid >> 8, dq = tid & 255;
        const signed char* src = xq + (size_t)(b0 + bq) * 12288 + dq;
        signed char* dst = &lXqT[bq][dq][0];
        #pragma unroll
        for (int j = 0; j < 48; ++j) dst[j] = src[(size_t)j * 256];
        *(int4*)(dst + 48) = (int4){0, 0, 0, 0};
    }

    // loop-invariant per-lane constants (both batches)
    const float xwv0 = (lane < 48) ? xw[(size_t)b0 * 48 + lane] : 0.f;
    const float xwv1 = (lane < 48) ? xw[(size_t)(b0 + 1) * 48 + lane] : 0.f;
    const float xsv0 = (lane < 48) ? xs[(size_t)b0 * 48 + lane] : 0.f;
    const float xsv1 = (lane < 48) ? xs[(size_t)(b0 + 1) * 48 + lane] : 0.f;
    const float qsv = (lane < 48) ? qAg[768 + lane] : 0.f;   // score dequant scale
    const float bsv = (lane < 48) ? b_h[lane] : 0.f;         // score bias
    const unsigned long long cb0 = condbits[b0];
    const unsigned long long cb1 = condbits[b0 + 1];

    // GRU dequant/bias constants (per-lane loop-invariant) in registers
    const float qA0r = qAg[c0], qA0z = qAg[256 + c0], qA0n = qAg[512 + c0];
    const float bA0r = b_hh[c0], bA0z = b_hh[256 + c0], bA0n = b_hh[512 + c0];
    const float qC0r = qCg[c0], qC0z = qCg[256 + c0], qC0n = qCg[512 + c0];
    const float bC0r = b_ih[c0], bC0z = b_ih[256 + c0], bC0n = b_ih[512 + c0];
    const float qA1r = qAg[c1], qA1z = qAg[256 + c1], qA1n = qAg[512 + c1];
    const float bA1r = b_hh[c1], bA1z = b_hh[256 + c1], bA1n = b_hh[512 + c1];
    const float qC1r = qCg[c1], qC1z = qCg[256 + c1], qC1n = qCg[512 + c1];
    const float bC1r = b_ih[c1], bC1z = b_ih[256 + c1], bC1n = b_ih[512 + c1];

    // ---- resident weights: registers/AGPRs (9 tiles per wave) ----
    const int fro = row16 * 256 + kg * 16;
    i32x4 wa0[3][4], wa1[3][4], wc0[3][4];
    #pragma unroll
    for (int t = 0; t < 3; ++t) {
        const signed char* p0 = W1q + (size_t)(t * 16 + w) * 4096 + fro;
        const signed char* p1 = W1q + (size_t)(t * 16 + g1) * 4096 + fro;
        const signed char* p2 = W2q + (size_t)(t * 16 + w) * 4096 + fro;
        #pragma unroll
        for (int s = 0; s < 4; ++s) {
            wa0[t][s] = *(const i32x4*)(p0 + s * 64);
            wa1[t][s] = *(const i32x4*)(p1 + s * 64);
            wc0[t][s] = *(const i32x4*)(p2 + s * 64);
        }
    }
    // ---- resident weights: LDS (slab g1 W2 tiles + score tiles), swizzled ----
    #pragma unroll
    for (int t = 0; t < 3; ++t) {
        const signed char* src = W2q + (size_t)(t * 16 + g1) * 4096 + fro;
        signed char* dst = &lWc[w][t][row16 * 256];
        #pragma unroll
        for (int s = 0; s < 4; ++s)
            *(i32x4*)(dst + ((kg * 16 + s * 64) ^ swz)) = *(const i32x4*)(src + s * 64);
    }
    if (w < 3) {
        const signed char* src = W1q + (size_t)(48 + w) * 4096 + fro;
        signed char* dst = &lWs[w][row16 * 256];
        #pragma unroll
        for (int s = 0; s < 4; ++s)
            *(i32x4*)(dst + ((kg * 16 + s * 64) ^ swz)) = *(const i32x4*)(src + s * 64);
    }
    __syncthreads();

    float h0[2] = {0.f, 0.f};
    float h1[2] = {0.f, 0.f};
    float ascale0 = 0.f, ascale1 = 0.f;

    for (int i = 0; i < 48; ++i) {
        // ---- Phase A: per-wave score MFMAs first, gates retire in their shadow -
        i32x4 av[4];
        #pragma unroll
        for (int s = 0; s < 4; ++s) av[s] = *(const i32x4*)(&lH8[row16][0] + kg * 16 + s * 64);
        i32x4 sv0 = {0,0,0,0}, sv1 = {0,0,0,0}, sv2 = {0,0,0,0};
        #pragma unroll
        for (int s = 0; s < 4; ++s) {
            int off = (kg * 16 + s * 64) ^ swz;
            i32x4 q0 = *(const i32x4*)(&lWs[0][row16 * 256] + off);
            i32x4 q1 = *(const i32x4*)(&lWs[1][row16 * 256] + off);
            i32x4 q2 = *(const i32x4*)(&lWs[2][row16 * 256] + off);
            sv0 = __builtin_amdgcn_mfma_i32_16x16x64_i8(av[s], q0, sv0, 0, 0, 0);
            sv1 = __builtin_amdgcn_mfma_i32_16x16x64_i8(av[s], q1, sv1, 0, 0, 0);
            sv2 = __builtin_amdgcn_mfma_i32_16x16x64_i8(av[s], q2, sv2, 0, 0, 0);
        }
        i32x4 aR0 = {0,0,0,0}, aZ0 = {0,0,0,0}, aN0 = {0,0,0,0};
        i32x4 aR1 = {0,0,0,0}, aZ1 = {0,0,0,0}, aN1 = {0,0,0,0};
        mfma4r(av, wa0[0], aR0); mfma4r(av, wa0[1], aZ0); mfma4r(av, wa0[2], aN0);
        mfma4r(av, wa1[0], aR1); mfma4r(av, wa1[1], aZ1); mfma4r(av, wa1[2], aN1);

        // ---- B1: both batches' softmax in-register; a' quantized to i8 ----
        #define SOFTMAX_REP(E, XWV, XSV, CB, ASC)                                   \
        {                                                                           \
            float s0 = (float)sv0[E], s1_ = (float)sv1[E], s2_ = (float)sv2[E];     \
            float v0 = __shfl(s0, row16);                                           \
            float v1 = __shfl(s1_, row16);                                          \
            float v2 = __shfl(s2_, row16);                                          \
            float raw = (lane < 16) ? v0 : ((lane < 32) ? v1 : v2);                 \
            float val = -3.0e38f;                                                   \
            if (lane < 48) {                                                        \
                val = raw * qsv + bsv;                                              \
                bool cb = (CB >> i) & 1ull;                                         \
                if (lane == i || (cb && lane < i)) val += XWV;                      \
            }                                                                       \
            float mx = val;                                                         \
            _Pragma("unroll")                                                       \
            for (int o = 32; o; o >>= 1) mx = fmaxf(mx, __shfl_xor(mx, o));         \
            float ex = (lane < 48) ? __expf(val - mx) : 0.f;                        \
            float pvs = ex * XSV;                                                   \
            float sm = ex, mp = pvs;                                                \
            _Pragma("unroll")                                                       \
            for (int o = 32; o; o >>= 1) {                                          \
                sm += __shfl_xor(sm, o);                                            \
                mp = fmaxf(mp, __shfl_xor(mp, o));                                  \
            }                                                                       \
            float rqn = (mp > 0.f) ? 127.f / mp : 0.f;                              \
            int ai = __float2int_rn(pvs * rqn);                                     \
            if (lane < 48) lAq[w][E][lane] = (signed char)ai;                       \
            ASC = mp / (127.f * sm);                                                \
        }
        SOFTMAX_REP(0, xwv0, xsv0, cb0, ascale0)
        SOFTMAX_REP(1, xwv1, xsv1, cb1, ascale1)
        #undef SOFTMAX_REP

        // ---- B2 via MFMA: ctx_int = x^T(A) x a'(B), one K=64 MFMA per (tile,b) --
        {
            i32x4 ba0 = *(const i32x4*)(&lAq[w][0][kg * 16]);
            i32x4 ba1 = *(const i32x4*)(&lAq[w][1][kg * 16]);
            #pragma unroll
            for (int tt = 0; tt < 2; ++tt) {
                const int dt = (w * 2 + tt) * 16;
                i32x4 xa0 = *(const i32x4*)(&lXqT[0][dt + row16][kg * 16]);
                i32x4 xa1 = *(const i32x4*)(&lXqT[1][dt + row16][kg * 16]);
                i32x4 zc = {0, 0, 0, 0};
                i32x4 c0v = __builtin_amdgcn_mfma_i32_16x16x64_i8(xa0, ba0, zc, 0, 0, 0);
                i32x4 c1v = __builtin_amdgcn_mfma_i32_16x16x64_i8(xa1, ba1, zc, 0, 0, 0);
                if (row16 == 0) {
                    #pragma unroll
                    for (int e = 0; e < 4; ++e) {
                        int d = dt + kg * 4 + e;
                        float f0 = (float)c0v[e] * ascale0 * CS;
                        float f1 = (float)c1v[e] * ascale1 * CS;
                        lX8[0][d] = (signed char)__float2int_rn(fminf(fmaxf(f0, -127.f), 127.f));
                        lX8[1][d] = (signed char)__float2int_rn(fminf(fmaxf(f1, -127.f), 127.f));
                    }
                }
            }
        }
        __syncthreads();

        // ---- Phase C + GRU (C-fragment layout, rows 0-1; consts in regs) ----
        i32x4 cv[4];
        #pragma unroll
        for (int s = 0; s < 4; ++s) cv[s] = *(const i32x4*)(&lX8[row16][0] + kg * 16 + s * 64);
        {   // slab 0: C weights from registers
            i32x4 cr = {0,0,0,0}, cz = {0,0,0,0}, cn = {0,0,0,0};
            mfma4r(cv, wc0[0], cr); mfma4r(cv, wc0[1], cz); mfma4r(cv, wc0[2], cn);
            #pragma unroll
            for (int e = 0; e < 2; ++e) {
                float gr = (float)aR0[e] * qA0r + bA0r + (float)cr[e] * qC0r + bC0r;
                float gz = (float)aZ0[e] * qA0z + bA0z + (float)cz[e] * qC0z + bC0z;
                float gh = (float)aN0[e] * qA0n + bA0n;
                float gn = (float)cn[e] * qC0n + bC0n;
                float r = 1.f / (1.f + __expf(-gr));
                float z = 1.f / (1.f + __expf(-gz));
                float nn = 1.f - 2.f / (__expf(2.f * (gn + r * gh)) + 1.f);
                float hp = (1.f - z) * nn + z * h0[e];
                h0[e] = hp;
                if (kg == 0)
                    lH8[e][c0] = (signed char)__float2int_rn(fminf(fmaxf(hp, -1.f), 1.f) * 127.f);
            }
        }
        {   // slab 1: C weights from LDS (swizzled)
            i32x4 cr = {0,0,0,0}, cz = {0,0,0,0}, cn = {0,0,0,0};
            #pragma unroll
            for (int s = 0; s < 4; ++s) {
                int off = (kg * 16 + s * 64) ^ swz;
                i32x4 br = *(const i32x4*)(&lWc[w][0][row16 * 256] + off);
                i32x4 bz = *(const i32x4*)(&lWc[w][1][row16 * 256] + off);
                i32x4 bn = *(const i32x4*)(&lWc[w][2][row16 * 256] + off);
                cr = __builtin_amdgcn_mfma_i32_16x16x64_i8(cv[s], br, cr, 0, 0, 0);
                cz = __builtin_amdgcn_mfma_i32_16x16x64_i8(cv[s], bz, cz, 0, 0, 0);
                cn = __builtin_amdgcn_mfma_i32_16x16x64_i8(cv[s], bn, cn, 0, 0, 0);
            }
            #pragma unroll
            for (int e = 0; e < 2; ++e) {
                float gr = (float)aR1[e] * qA1r + bA1r + (float)cr[e] * qC1r + bC1r;
                float gz = (float)aZ1[e] * qA1z + bA1z + (float)cz[e] * qC1z + bC1z;
                float gh = (float)aN1[e] * qA1n + bA1n;
                float gn = (float)cn[e] * qC1n + bC1n;
                float r = 1.f / (1.f + __expf(-gr));
                float z = 1.f / (1.f + __expf(-gz));
                float nn = 1.f - 2.f / (__expf(2.f * (gn + r * gh)) + 1.f);
                float hp = (1.f - z) * nn + z * h1[e];
                h1[e] = hp;
                if (kg == 0)
                    lH8[e][c1] = (signed char)__float2int_rn(fminf(fmaxf(hp, -1.f), 1.f) * 127.f);
            }
        }
        __syncthreads();
    }

    // ---- epilogue: y = sigmoid((hF + se) . w_out + b_out) ----
    if (kg == 0) {
        float p[2];
        #pragma unroll
        for (int e = 0; e < 2; ++e) {
            int b = b0 + e;
            p[e] = (h0[e] + se[(size_t)b * 256 + c0]) * w_out[c0]
                 + (h1[e] + se[(size_t)b * 256 + c1]) * w_out[c1];
        }
        #pragma unroll
        for (int o = 1; o < 16; o <<= 1) {
            #pragma unroll
            for (int e = 0; e < 2; ++e) p[e] += __shfl_xor(p[e], o);
        }
        if (row16 == 0) {
            #pragma unroll
            for (int e = 0; e < 2; ++e) lRed[w][e] = p[e];
        }
    }
    __syncthreads();
    if (tid < 2) {
        float sum = 0.f;
        #pragma unroll
        for (int q = 0; q < 8; ++q) sum += lRed[q][tid];
        out[b0 + tid] = 1.f / (1.f + __expf(-(sum + b_out[0])));
    }
}

extern "C" void kernel_launch(void* const* d_in, const int* in_sizes, int n_in,
                              void* d_out, int out_size, void* d_ws, size_t ws_size,
                              hipStream_t stream) {
    const float* x1   = (const float*)d_in[0];
    const float* x2   = (const float*)d_in[1];
    const float* s    = (const float*)d_in[2];
    const float* w_e1 = (const float*)d_in[3];
    const float* b_e1 = (const float*)d_in[4];
    const float* w_e2 = (const float*)d_in[5];
    const float* b_e2 = (const float*)d_in[6];
    const float* w_s  = (const float*)d_in[7];
    const float* b_s  = (const float*)d_in[8];
    const float* w_x  = (const float*)d_in[9];
    const float* w_h  = (const float*)d_in[10];
    const float* b_h  = (const float*)d_in[11];
    const float* w_ih = (const float*)d_in[12];
    const float* w_hh = (const float*)d_in[13];
    const float* b_ih = (const float*)d_in[14];
    const float* b_hh = (const float*)d_in[15];
    const float* w_out = (const float*)d_in[16];
    const float* b_out = (const float*)d_in[17];
    float* out = (float*)d_out;

    char* ws = (char*)d_ws;
    size_t off = 0;
    auto alloc = [&](size_t bytes) -> void* {
        void* p = ws + off;
        off = (off + bytes + 255) & ~(size_t)255;
        return p;
    };
    short* xb = (short*)alloc((size_t)B_ * L_ * D_ * 2);
    signed char* xq = (signed char*)alloc((size_t)B_ * L_ * D_);
    float* xs = (float*)alloc((size_t)B_ * L_ * 4);
    signed char* W1q = (signed char*)alloc(896 * 256);
    signed char* W2q = (signed char*)alloc(768 * 256);
    float* qA = (float*)alloc(816 * 4);
    float* qC = (float*)alloc(768 * 4);
    float* c0 = (float*)alloc((size_t)B_ * L_ * 4);
    float* xw = (float*)alloc((size_t)B_ * L_ * 4);
    unsigned long long* cb = (unsigned long long*)alloc(B_ * 8);
    float* se = (float*)alloc((size_t)B_ * D_ * 4);

    hipLaunchKernelGGL(k_prep, dim3(396), dim3(256), 0, stream,
                       w_hh, w_h, w_ih, W1q, W2q, qA, qC);
    hipLaunchKernelGGL(k_embed, dim3(384), dim3(512), 0, stream,
                       x1, x2, w_e1, b_e1, w_e2, b_e2, xb, c0);
    hipLaunchKernelGGL(k_quant, dim3(6144), dim3(256), 0, stream,
                       xb, w_x, xq, xs, xw);
    hipLaunchKernelGGL(k_aux2, dim3(512), dim3(256), 0, stream,
                       c0, s, w_s, b_s, cb, se);
    hipLaunchKernelGGL(k_scan, dim3(256), dim3(512), 0, stream,
                       W1q, W2q, qA, qC, b_hh, b_h, b_ih, xq, xs, xw, cb, se,
                       w_out, b_out, out);
}

// Round 17
// 231.099 us; speedup vs baseline: 1.1571x; 1.1571x over previous
//
#include <hip/hip_runtime.h>
#include <stdint.h>

#define B_ 512
#define L_ 48
#define D_ 256

typedef __attribute__((ext_vector_type(8))) short bf16x8;
typedef __attribute__((ext_vector_type(4))) short bf16x4;
typedef __attribute__((ext_vector_type(4))) float f32x4;
typedef __attribute__((ext_vector_type(4))) int i32x4;

__device__ __forceinline__ short f2bf(float f) {
    union { float f; unsigned u; } v; v.f = f;
    unsigned u = v.u;
    unsigned r = (u + 0x7FFFu + ((u >> 16) & 1u)) >> 16;
    return (short)r;
}
__device__ __forceinline__ float bf2f(short s) {
    union { unsigned u; float f; } v; v.u = ((unsigned)(unsigned short)s) << 16;
    return v.f;
}

// -------- weight prep: per-row symmetric i8 quant of [w_hh;w_h] and w_ih -------
__global__ __launch_bounds__(256) void k_prep(const float* __restrict__ w_hh,
                                              const float* __restrict__ w_h,
                                              const float* __restrict__ w_ih,
                                              signed char* __restrict__ W1q,
                                              signed char* __restrict__ W2q,
                                              float* __restrict__ qA,
                                              float* __restrict__ qC) {
    int w = threadIdx.x >> 6, lane = threadIdx.x & 63;
    int R = blockIdx.x * 4 + w;
    if (R >= 1584) return;
    const float* src;
    signed char* dst;
    bool isA = (R < 816);
    if (R < 768)      { src = w_hh + (size_t)R * 256;         dst = W1q + (size_t)R * 256; }
    else if (R < 816) { src = w_h + (size_t)(R - 768) * 256;  dst = W1q + (size_t)R * 256; }
    else              { src = w_ih + (size_t)(R - 816) * 256; dst = W2q + (size_t)(R - 816) * 256; }
    float4 v = *(const float4*)(src + lane * 4);
    float m = fmaxf(fmaxf(fabsf(v.x), fabsf(v.y)), fmaxf(fabsf(v.z), fabsf(v.w)));
    #pragma unroll
    for (int o = 32; o; o >>= 1) m = fmaxf(m, __shfl_xor(m, o));
    float sc = (m > 0.f) ? 127.f / m : 0.f;
    int b0 = __float2int_rn(v.x * sc), b1 = __float2int_rn(v.y * sc);
    int b2 = __float2int_rn(v.z * sc), b3 = __float2int_rn(v.w * sc);
    unsigned word = (unsigned)(b0 & 255) | ((unsigned)(b1 & 255) << 8) |
                    ((unsigned)(b2 & 255) << 16) | ((unsigned)(b3 & 255) << 24);
    ((unsigned*)dst)[lane] = word;
    if (lane == 0) {
        if (isA) qA[R] = m / (127.f * 127.f);
        else     qC[R - 816] = m * 8.f / (127.f * 127.f);
    }
}

// ---------------- embedding GEMM: x = relu(x1@we1^T+b1) + relu(x2@we2^T+b2) ----
__device__ __forceinline__ void gemm_pass(const float* __restrict__ X,
                                          const float* __restrict__ W,
                                          short (*sA)[40], short (*sB)[40],
                                          int m0, int n0, int srow, int sseg,
                                          int mf, int nf, int row16, int kg,
                                          f32x4 (&acc)[2][4]) {
    for (int k0 = 0; k0 < 512; k0 += 32) {
        __syncthreads();
        {
            const float* src = X + (size_t)(m0 + srow) * 512 + k0 + sseg * 8;
            float4 p0 = *(const float4*)(src);
            float4 p1 = *(const float4*)(src + 4);
            bf16x8 v;
            v[0] = f2bf(p0.x); v[1] = f2bf(p0.y); v[2] = f2bf(p0.z); v[3] = f2bf(p0.w);
            v[4] = f2bf(p1.x); v[5] = f2bf(p1.y); v[6] = f2bf(p1.z); v[7] = f2bf(p1.w);
            *(bf16x8*)&sA[srow][sseg * 8] = v;
        }
        {
            const float* src = W + (size_t)(n0 + srow) * 512 + k0 + sseg * 8;
            float4 p0 = *(const float4*)(src);
            float4 p1 = *(const float4*)(src + 4);
            bf16x8 v;
            v[0] = f2bf(p0.x); v[1] = f2bf(p0.y); v[2] = f2bf(p0.z); v[3] = f2bf(p0.w);
            v[4] = f2bf(p1.x); v[5] = f2bf(p1.y); v[6] = f2bf(p1.z); v[7] = f2bf(p1.w);
            *(bf16x8*)&sB[srow][sseg * 8] = v;
        }
        __syncthreads();
        bf16x8 a0 = *(bf16x8*)&sA[(mf + 0) * 16 + row16][kg * 8];
        bf16x8 a1 = *(bf16x8*)&sA[(mf + 1) * 16 + row16][kg * 8];
        #pragma unroll
        for (int j = 0; j < 4; ++j) {
            bf16x8 bv = *(bf16x8*)&sB[(nf + j) * 16 + row16][kg * 8];
            acc[0][j] = __builtin_amdgcn_mfma_f32_16x16x32_bf16(a0, bv, acc[0][j], 0, 0, 0);
            acc[1][j] = __builtin_amdgcn_mfma_f32_16x16x32_bf16(a1, bv, acc[1][j], 0, 0, 0);
        }
    }
}

// pass 2 variant: also accumulates exact-fp32 channel-0 dot of x2 rows vs w_e2[0]
__device__ __forceinline__ void gemm_pass_c0(const float* __restrict__ X,
                                             const float* __restrict__ W,
                                             const float* __restrict__ we2r0,
                                             bool doC0, float& c0acc,
                                             short (*sA)[40], short (*sB)[40],
                                             int m0, int n0, int srow, int sseg,
                                             int mf, int nf, int row16, int kg,
                                             f32x4 (&acc)[2][4]) {
    for (int k0 = 0; k0 < 512; k0 += 32) {
        __syncthreads();
        {
            const float* src = X + (size_t)(m0 + srow) * 512 + k0 + sseg * 8;
            float4 p0 = *(const float4*)(src);
            float4 p1 = *(const float4*)(src + 4);
            if (doC0) {
                const float* wr = we2r0 + k0 + sseg * 8;
                c0acc += p0.x * wr[0] + p0.y * wr[1] + p0.z * wr[2] + p0.w * wr[3]
                       + p1.x * wr[4] + p1.y * wr[5] + p1.z * wr[6] + p1.w * wr[7];
            }
            bf16x8 v;
            v[0] = f2bf(p0.x); v[1] = f2bf(p0.y); v[2] = f2bf(p0.z); v[3] = f2bf(p0.w);
            v[4] = f2bf(p1.x); v[5] = f2bf(p1.y); v[6] = f2bf(p1.z); v[7] = f2bf(p1.w);
            *(bf16x8*)&sA[srow][sseg * 8] = v;
        }
        {
            const float* src = W + (size_t)(n0 + srow) * 512 + k0 + sseg * 8;
            float4 p0 = *(const float4*)(src);
            float4 p1 = *(const float4*)(src + 4);
            bf16x8 v;
            v[0] = f2bf(p0.x); v[1] = f2bf(p0.y); v[2] = f2bf(p0.z); v[3] = f2bf(p0.w);
            v[4] = f2bf(p1.x); v[5] = f2bf(p1.y); v[6] = f2bf(p1.z); v[7] = f2bf(p1.w);
            *(bf16x8*)&sB[srow][sseg * 8] = v;
        }
        __syncthreads();
        bf16x8 a0 = *(bf16x8*)&sA[(mf + 0) * 16 + row16][kg * 8];
        bf16x8 a1 = *(bf16x8*)&sA[(mf + 1) * 16 + row16][kg * 8];
        #pragma unroll
        for (int j = 0; j < 4; ++j) {
            bf16x8 bv = *(bf16x8*)&sB[(nf + j) * 16 + row16][kg * 8];
            acc[0][j] = __builtin_amdgcn_mfma_f32_16x16x32_bf16(a0, bv, acc[0][j], 0, 0, 0);
            acc[1][j] = __builtin_amdgcn_mfma_f32_16x16x32_bf16(a1, bv, acc[1][j], 0, 0, 0);
        }
    }
}

__global__ __launch_bounds__(512) void k_embed(const float* __restrict__ x1,
                                               const float* __restrict__ x2,
                                               const float* __restrict__ w_e1,
                                               const float* __restrict__ b_e1,
                                               const float* __restrict__ w_e2,
                                               const float* __restrict__ b_e2,
                                               short* __restrict__ xb,
                                               float* __restrict__ c0) {
    __shared__ short sA[128][40];
    __shared__ short sB[128][40];
    int bid = blockIdx.x;
    int mt = bid >> 1, nt = bid & 1;
    int m0 = mt * 128, n0 = nt * 128;
    int tid = threadIdx.x;
    int lane = tid & 63, w = tid >> 6;
    int mf = (w & 3) * 2;
    int nf = (w >> 2) * 4;
    int row16 = lane & 15, kg = lane >> 4;
    int srow = tid >> 2, sseg = tid & 3;

    f32x4 acc[2][4], keep[2][4];
    #pragma unroll
    for (int a = 0; a < 2; ++a)
        #pragma unroll
        for (int j = 0; j < 4; ++j) { acc[a][j] = {0.f, 0.f, 0.f, 0.f}; }

    gemm_pass(x1, w_e1, sA, sB, m0, n0, srow, sseg, mf, nf, row16, kg, acc);
    #pragma unroll
    for (int a = 0; a < 2; ++a)
        #pragma unroll
        for (int j = 0; j < 4; ++j) { keep[a][j] = acc[a][j]; acc[a][j] = {0.f, 0.f, 0.f, 0.f}; }

    float c0acc = 0.f;
    const bool doC0 = (nt == 0);
    gemm_pass_c0(x2, w_e2, w_e2, doC0, c0acc, sA, sB, m0, n0, srow, sseg, mf, nf, row16, kg, acc);

    if (doC0) {
        float t = c0acc;
        t += __shfl_xor(t, 1);
        t += __shfl_xor(t, 2);
        if (sseg == 0) c0[m0 + srow] = fmaxf(t + b_e2[0], 0.f);
    }

    #pragma unroll
    for (int a = 0; a < 2; ++a) {
        int mbase = m0 + (mf + a) * 16 + kg * 4;
        #pragma unroll
        for (int j = 0; j < 4; ++j) {
            int n = n0 + (nf + j) * 16 + row16;
            float be1 = b_e1[n], be2 = b_e2[n];
            #pragma unroll
            for (int e = 0; e < 4; ++e) {
                float v1 = fmaxf(keep[a][j][e] + be1, 0.f);
                float v2 = fmaxf(acc[a][j][e] + be2, 0.f);
                xb[(size_t)(mbase + e) * 256 + n] = f2bf(v1 + v2);
            }
        }
    }
}

// --------- quantize x rows to i8 (per-row scale) + fused xw = x . w_x ----------
__global__ __launch_bounds__(256) void k_quant(const short* __restrict__ xb,
                                               const float* __restrict__ w_x,
                                               signed char* __restrict__ xq,
                                               float* __restrict__ xs,
                                               float* __restrict__ xw) {
    int w = threadIdx.x >> 6, lane = threadIdx.x & 63;
    int row = blockIdx.x * 4 + w;
    const short* src = xb + (size_t)row * 256 + lane * 4;
    bf16x4 v = *(const bf16x4*)src;
    float f0 = bf2f(v.x), f1 = bf2f(v.y), f2 = bf2f(v.z), f3 = bf2f(v.w);
    float m = fmaxf(fmaxf(f0, f1), fmaxf(f2, f3));   // x >= 0
    float t = f0 * w_x[lane * 4] + f1 * w_x[lane * 4 + 1] +
              f2 * w_x[lane * 4 + 2] + f3 * w_x[lane * 4 + 3];
    #pragma unroll
    for (int o = 32; o; o >>= 1) {
        m = fmaxf(m, __shfl_xor(m, o));
        t += __shfl_xor(t, o);
    }
    float sc = (m > 0.f) ? 127.f / m : 0.f;
    int b0 = __float2int_rn(f0 * sc), b1 = __float2int_rn(f1 * sc);
    int b2 = __float2int_rn(f2 * sc), b3 = __float2int_rn(f3 * sc);
    unsigned word = (unsigned)(b0 & 255) | ((unsigned)(b1 & 255) << 8) |
                    ((unsigned)(b2 & 255) << 16) | ((unsigned)(b3 & 255) << 24);
    ((unsigned*)xq)[(size_t)row * 64 + lane] = word;
    if (lane == 0) { xs[row] = m / 127.f; xw[row] = t; }
}

// ------------- aux2: cond bitmasks per batch + se = s@w_s^T + b_s --------------
__global__ __launch_bounds__(256) void k_aux2(const float* __restrict__ c0,
                                              const float* __restrict__ s_in,
                                              const float* __restrict__ w_s,
                                              const float* __restrict__ b_s,
                                              unsigned long long* __restrict__ condbits,
                                              float* __restrict__ se) {
    __shared__ float sS[64];
    int b = blockIdx.x;
    int t = threadIdx.x;
    if (t < 64) sS[t] = s_in[b * 64 + t];
    __syncthreads();
    float acc = b_s[t];
    const float* wr = w_s + t * 64;
    #pragma unroll 8
    for (int kk = 0; kk < 64; ++kk) acc += sS[kk] * wr[kk];
    se[(size_t)b * 256 + t] = acc;
    if (t == 0) {
        unsigned long long bits = 0;
        bool run = true;
        const float* cr = c0 + (size_t)b * 48;
        for (int i = 0; i < 48; ++i) {
            if (run) bits |= (1ull << i);
            run = run && (cr[i] == 0.0f);
        }
        condbits[b] = bits;
    }
}

__device__ __forceinline__ void mfma4r(const i32x4 (&a)[4], const i32x4 (&b)[4], i32x4& acc) {
    #pragma unroll
    for (int s = 0; s < 4; ++s)
        acc = __builtin_amdgcn_mfma_i32_16x16x64_i8(a[s], b[s], acc, 0, 0, 0);
}

// ---- persistent scan v8: 2 barriers/step; per-wave scores; transposed x LDS ----
// 256 blocks x 2 batches, 8 waves. Every wave computes its batch's 3 score
// MFMAs redundantly (scores never leave registers: 3-shuffle rearrange ->
// softmax, no cross-wave sync). B2 reads transposed conflict-free lXqT with
// 4-byte vector loads. GRU in C-fragment layout. 2 barriers/step.
__global__ __launch_bounds__(512, 1) void k_scan(const signed char* __restrict__ W1q,
                                                 const signed char* __restrict__ W2q,
                                                 const float* __restrict__ qAg,
                                                 const float* __restrict__ qCg,
                                                 const float* __restrict__ b_hh,
                                                 const float* __restrict__ b_h,
                                                 const float* __restrict__ b_ih,
                                                 const signed char* __restrict__ xq,
                                                 const float* __restrict__ xs,
                                                 const float* __restrict__ xw,
                                                 const unsigned long long* __restrict__ condbits,
                                                 const float* __restrict__ se,
                                                 const float* __restrict__ w_out,
                                                 const float* __restrict__ b_out,
                                                 float* __restrict__ out) {
    __shared__ signed char lWc[8][3][4096];    // slab 8+w: W2 r/z/hn tiles, swizzled
    __shared__ signed char lWs[3][4096];       // score tiles (w_h), swizzled
    __shared__ signed char lXqT[2][256][52];   // x i8 TRANSPOSED, pitch 52 (bank-free)
    __shared__ signed char lH8[16][272];       // h as i8 (rows 2-15 stay zero)
    __shared__ signed char lX8[16][272];       // ctx as i8 (rows 2-15 stay zero)
    __shared__ float lTw[8][52];               // wave-private softmax*scale values
    __shared__ float lbA[816], lqA[816], lbC[768], lqC[768];
    __shared__ float lRed[8][2];

    const int tid = threadIdx.x;
    const int w = tid >> 6, lane = tid & 63;
    const int row16 = lane & 15, kg = lane >> 4;
    const int b0 = blockIdx.x * 2;
    const int g1 = 8 + w;
    const int c0 = w * 16 + row16, c1 = g1 * 16 + row16;
    const int swz = (row16 & 7) << 4;
    const float CS = 127.f / 8.f;
    const int mb = w >> 2;                 // this wave's batch (0 or 1)
    const int dimb = ((w & 3) << 6) + lane; // this thread's B2 dim (0..255)

    for (int t = tid; t < 816; t += 512) {
        lbA[t] = (t < 768) ? b_hh[t] : b_h[t - 768];
        lqA[t] = qAg[t];
    }
    for (int t = tid; t < 768; t += 512) { lbC[t] = b_ih[t]; lqC[t] = qCg[t]; }
    for (int t = tid; t < 1088; t += 512) {   // zero full lH8 and lX8
        ((int*)lH8)[t] = 0;
        ((int*)lX8)[t] = 0;
    }
    {   // stage x TRANSPOSED: thread -> (batch tid>>8, dim tid&255), 48 j-bytes
        int bq = tid >> 8, dq = tid & 255;
        const signed char* src = xq + (size_t)(b0 + bq) * 12288 + dq;
        signed char* dst = &lXqT[bq][dq][0];
        #pragma unroll
        for (int j = 0; j < 48; ++j) dst[j] = src[(size_t)j * 256];
    }

    // loop-invariant per-lane constants
    const float xwv = (lane < 48) ? xw[(size_t)(b0 + mb) * 48 + lane] : 0.f;
    const float xsv = (lane < 48) ? xs[(size_t)(b0 + mb) * 48 + lane] : 0.f;
    const float qsv = (lane < 48) ? qAg[768 + lane] : 0.f;   // score dequant scale
    const float bsv = (lane < 48) ? b_h[lane] : 0.f;         // score bias
    const unsigned long long cbits = condbits[b0 + mb];

    // ---- resident weights: registers/AGPRs (9 tiles per wave) ----
    const int fro = row16 * 256 + kg * 16;
    i32x4 wa0[3][4], wa1[3][4], wc0[3][4];
    #pragma unroll
    for (int t = 0; t < 3; ++t) {
        const signed char* p0 = W1q + (size_t)(t * 16 + w) * 4096 + fro;
        const signed char* p1 = W1q + (size_t)(t * 16 + g1) * 4096 + fro;
        const signed char* p2 = W2q + (size_t)(t * 16 + w) * 4096 + fro;
        #pragma unroll
        for (int s = 0; s < 4; ++s) {
            wa0[t][s] = *(const i32x4*)(p0 + s * 64);
            wa1[t][s] = *(const i32x4*)(p1 + s * 64);
            wc0[t][s] = *(const i32x4*)(p2 + s * 64);
        }
    }
    // ---- resident weights: LDS (slab g1 W2 tiles + score tiles), swizzled ----
    #pragma unroll
    for (int t = 0; t < 3; ++t) {
        const signed char* src = W2q + (size_t)(t * 16 + g1) * 4096 + fro;
        signed char* dst = &lWc[w][t][row16 * 256];
        #pragma unroll
        for (int s = 0; s < 4; ++s)
            *(i32x4*)(dst + ((kg * 16 + s * 64) ^ swz)) = *(const i32x4*)(src + s * 64);
    }
    if (w < 3) {
        const signed char* src = W1q + (size_t)(48 + w) * 4096 + fro;
        signed char* dst = &lWs[w][row16 * 256];
        #pragma unroll
        for (int s = 0; s < 4; ++s)
            *(i32x4*)(dst + ((kg * 16 + s * 64) ^ swz)) = *(const i32x4*)(src + s * 64);
    }
    __syncthreads();

    float h0[2] = {0.f, 0.f};
    float h1[2] = {0.f, 0.f};

    for (int i = 0; i < 48; ++i) {
        // ---- Phase A: per-wave score MFMAs first, gates retire in their shadow -
        i32x4 av[4];
        #pragma unroll
        for (int s = 0; s < 4; ++s) av[s] = *(const i32x4*)(&lH8[row16][0] + kg * 16 + s * 64);
        i32x4 sv0 = {0,0,0,0}, sv1 = {0,0,0,0}, sv2 = {0,0,0,0};
        #pragma unroll
        for (int s = 0; s < 4; ++s) {
            int off = (kg * 16 + s * 64) ^ swz;
            i32x4 q0 = *(const i32x4*)(&lWs[0][row16 * 256] + off);
            i32x4 q1 = *(const i32x4*)(&lWs[1][row16 * 256] + off);
            i32x4 q2 = *(const i32x4*)(&lWs[2][row16 * 256] + off);
            sv0 = __builtin_amdgcn_mfma_i32_16x16x64_i8(av[s], q0, sv0, 0, 0, 0);
            sv1 = __builtin_amdgcn_mfma_i32_16x16x64_i8(av[s], q1, sv1, 0, 0, 0);
            sv2 = __builtin_amdgcn_mfma_i32_16x16x64_i8(av[s], q2, sv2, 0, 0, 0);
        }
        i32x4 aR0 = {0,0,0,0}, aZ0 = {0,0,0,0}, aN0 = {0,0,0,0};
        i32x4 aR1 = {0,0,0,0}, aZ1 = {0,0,0,0}, aN1 = {0,0,0,0};
        mfma4r(av, wa0[0], aR0); mfma4r(av, wa0[1], aZ0); mfma4r(av, wa0[2], aN0);
        mfma4r(av, wa1[0], aR1); mfma4r(av, wa1[1], aZ1); mfma4r(av, wa1[2], aN1);

        // ---- B1 (fully in-register, NO barrier): rearrange scores + softmax ----
        {
            float e00 = (float)sv0[0], e10 = (float)sv0[1];
            float e01 = (float)sv1[0], e11 = (float)sv1[1];
            float e02 = (float)sv2[0], e12 = (float)sv2[1];
            float s0 = mb ? e10 : e00;
            float s1 = mb ? e11 : e01;
            float s2 = mb ? e12 : e02;
            float v0 = __shfl(s0, row16);
            float v1 = __shfl(s1, row16);
            float v2 = __shfl(s2, row16);
            float raw = (lane < 16) ? v0 : ((lane < 32) ? v1 : v2);
            float val = -3.0e38f;
            if (lane < 48) {
                val = raw * qsv + bsv;
                bool cb = (cbits >> i) & 1ull;
                if (lane == i || (cb && lane < i)) val += xwv;
            }
            float mx = val;
            #pragma unroll
            for (int o = 32; o; o >>= 1) mx = fmaxf(mx, __shfl_xor(mx, o));
            float ex = (lane < 48) ? __expf(val - mx) : 0.f;
            float sm = ex;
            #pragma unroll
            for (int o = 32; o; o >>= 1) sm += __shfl_xor(sm, o);
            if (lane < 48) lTw[w][lane] = (ex / sm) * xsv;
        }
        // ---- B2: ctx[dimb] = sum_{j<=i} a_j*s_j * x[b,j,dimb], vectorized ----
        {
            const float* tw = lTw[w];
            const signed char* xv = &lXqT[mb][dimb][0];
            float acc = 0.f;
            int j = 0;
            for (; j + 3 <= i; j += 4) {
                union { int v; signed char c[4]; } pk;
                pk.v = *(const int*)(xv + j);
                float4 t4 = *(const float4*)(tw + j);
                acc += t4.x * (float)pk.c[0] + t4.y * (float)pk.c[1]
                     + t4.z * (float)pk.c[2] + t4.w * (float)pk.c[3];
            }
            for (; j <= i; ++j) acc += tw[j] * (float)xv[j];
            lX8[mb][dimb] = (signed char)__float2int_rn(fminf(fmaxf(acc * CS, -127.f), 127.f));
        }
        __syncthreads();

        // ---- Phase C + GRU (C-fragment layout, rows 0-1) ----
        i32x4 cv[4];
        #pragma unroll
        for (int s = 0; s < 4; ++s) cv[s] = *(const i32x4*)(&lX8[row16][0] + kg * 16 + s * 64);
        {   // slab 0: C weights from registers
            i32x4 cr = {0,0,0,0}, cz = {0,0,0,0}, cn = {0,0,0,0};
            mfma4r(cv, wc0[0], cr); mfma4r(cv, wc0[1], cz); mfma4r(cv, wc0[2], cn);
            #pragma unroll
            for (int e = 0; e < 2; ++e) {
                float gr = (float)aR0[e] * lqA[c0]       + lbA[c0]       + (float)cr[e] * lqC[c0]       + lbC[c0];
                float gz = (float)aZ0[e] * lqA[256 + c0] + lbA[256 + c0] + (float)cz[e] * lqC[256 + c0] + lbC[256 + c0];
                float gh = (float)aN0[e] * lqA[512 + c0] + lbA[512 + c0];
                float gn = (float)cn[e] * lqC[512 + c0]  + lbC[512 + c0];
                float r = 1.f / (1.f + __expf(-gr));
                float z = 1.f / (1.f + __expf(-gz));
                float nn = 1.f - 2.f / (__expf(2.f * (gn + r * gh)) + 1.f);
                float hp = (1.f - z) * nn + z * h0[e];
                h0[e] = hp;
                if (kg == 0)
                    lH8[e][c0] = (signed char)__float2int_rn(fminf(fmaxf(hp, -1.f), 1.f) * 127.f);
            }
        }
        {   // slab 1: C weights from LDS (swizzled)
            i32x4 cr = {0,0,0,0}, cz = {0,0,0,0}, cn = {0,0,0,0};
            #pragma unroll
            for (int s = 0; s < 4; ++s) {
                int off = (kg * 16 + s * 64) ^ swz;
                i32x4 br = *(const i32x4*)(&lWc[w][0][row16 * 256] + off);
                i32x4 bz = *(const i32x4*)(&lWc[w][1][row16 * 256] + off);
                i32x4 bn = *(const i32x4*)(&lWc[w][2][row16 * 256] + off);
                cr = __builtin_amdgcn_mfma_i32_16x16x64_i8(cv[s], br, cr, 0, 0, 0);
                cz = __builtin_amdgcn_mfma_i32_16x16x64_i8(cv[s], bz, cz, 0, 0, 0);
                cn = __builtin_amdgcn_mfma_i32_16x16x64_i8(cv[s], bn, cn, 0, 0, 0);
            }
            #pragma unroll
            for (int e = 0; e < 2; ++e) {
                float gr = (float)aR1[e] * lqA[c1]       + lbA[c1]       + (float)cr[e] * lqC[c1]       + lbC[c1];
                float gz = (float)aZ1[e] * lqA[256 + c1] + lbA[256 + c1] + (float)cz[e] * lqC[256 + c1] + lbC[256 + c1];
                float gh = (float)aN1[e] * lqA[512 + c1] + lbA[512 + c1];
                float gn = (float)cn[e] * lqC[512 + c1]  + lbC[512 + c1];
                float r = 1.f / (1.f + __expf(-gr));
                float z = 1.f / (1.f + __expf(-gz));
                float nn = 1.f - 2.f / (__expf(2.f * (gn + r * gh)) + 1.f);
                float hp = (1.f - z) * nn + z * h1[e];
                h1[e] = hp;
                if (kg == 0)
                    lH8[e][c1] = (signed char)__float2int_rn(fminf(fmaxf(hp, -1.f), 1.f) * 127.f);
            }
        }
        __syncthreads();
    }

    // ---- epilogue: y = sigmoid((hF + se) . w_out + b_out) ----
    if (kg == 0) {
        float p[2];
        #pragma unroll
        for (int e = 0; e < 2; ++e) {
            int b = b0 + e;
            p[e] = (h0[e] + se[(size_t)b * 256 + c0]) * w_out[c0]
                 + (h1[e] + se[(size_t)b * 256 + c1]) * w_out[c1];
        }
        #pragma unroll
        for (int o = 1; o < 16; o <<= 1) {
            #pragma unroll
            for (int e = 0; e < 2; ++e) p[e] += __shfl_xor(p[e], o);
        }
        if (row16 == 0) {
            #pragma unroll
            for (int e = 0; e < 2; ++e) lRed[w][e] = p[e];
        }
    }
    __syncthreads();
    if (tid < 2) {
        float sum = 0.f;
        #pragma unroll
        for (int q = 0; q < 8; ++q) sum += lRed[q][tid];
        out[b0 + tid] = 1.f / (1.f + __expf(-(sum + b_out[0])));
    }
}

extern "C" void kernel_launch(void* const* d_in, const int* in_sizes, int n_in,
                              void* d_out, int out_size, void* d_ws, size_t ws_size,
                              hipStream_t stream) {
    const float* x1   = (const float*)d_in[0];
    const float* x2   = (const float*)d_in[1];
    const float* s    = (const float*)d_in[2];
    const float* w_e1 = (const float*)d_in[3];
    const float* b_e1 = (const float*)d_in[4];
    const float* w_e2 = (const float*)d_in[5];
    const float* b_e2 = (const float*)d_in[6];
    const float* w_s  = (const float*)d_in[7];
    const float* b_s  = (const float*)d_in[8];
    const float* w_x  = (const float*)d_in[9];
    const float* w_h  = (const float*)d_in[10];
    const float* b_h  = (const float*)d_in[11];
    const float* w_ih = (const float*)d_in[12];
    const float* w_hh = (const float*)d_in[13];
    const float* b_ih = (const float*)d_in[14];
    const float* b_hh = (const float*)d_in[15];
    const float* w_out = (const float*)d_in[16];
    const float* b_out = (const float*)d_in[17];
    float* out = (float*)d_out;

    char* ws = (char*)d_ws;
    size_t off = 0;
    auto alloc = [&](size_t bytes) -> void* {
        void* p = ws + off;
        off = (off + bytes + 255) & ~(size_t)255;
        return p;
    };
    short* xb = (short*)alloc((size_t)B_ * L_ * D_ * 2);
    signed char* xq = (signed char*)alloc((size_t)B_ * L_ * D_);
    float* xs = (float*)alloc((size_t)B_ * L_ * 4);
    signed char* W1q = (signed char*)alloc(896 * 256);
    signed char* W2q = (signed char*)alloc(768 * 256);
    float* qA = (float*)alloc(816 * 4);
    float* qC = (float*)alloc(768 * 4);
    float* c0 = (float*)alloc((size_t)B_ * L_ * 4);
    float* xw = (float*)alloc((size_t)B_ * L_ * 4);
    unsigned long long* cb = (unsigned long long*)alloc(B_ * 8);
    float* se = (float*)alloc((size_t)B_ * D_ * 4);

    hipLaunchKernelGGL(k_prep, dim3(396), dim3(256), 0, stream,
                       w_hh, w_h, w_ih, W1q, W2q, qA, qC);
    hipLaunchKernelGGL(k_embed, dim3(384), dim3(512), 0, stream,
                       x1, x2, w_e1, b_e1, w_e2, b_e2, xb, c0);
    hipLaunchKernelGGL(k_quant, dim3(6144), dim3(256), 0, stream,
                       xb, w_x, xq, xs, xw);
    hipLaunchKernelGGL(k_aux2, dim3(512), dim3(256), 0, stream,
                       c0, s, w_s, b_s, cb, se);
    hipLaunchKernelGGL(k_scan, dim3(256), dim3(512), 0, stream,
                       W1q, W2q, qA, qC, b_hh, b_h, b_ih, xq, xs, xw, cb, se,
                       w_out, b_out, out);
}